// Round 14
// baseline (85.922 us; speedup 1.0000x reference)
//
#include <hip/hip_runtime.h>
#include <math.h>

// CapsuleLayer dynamic routing, factored (u_hat never materialized):
//   s[b,m,:] = ((Sum_n e_n in[b,n,:]) / (Sum_n e_n)) @ W[:,m,:], e_n = exp(logit)
//   logit linear in per-pass wv updates -> cumulative wv, no per-n state.
//   Pass 0 (uniform softmax) = plain column sum, S = 2048.
//   exp via exp2: cum stores wv * log2(e) (prescaled at tail, free).
//
// Plateau ledger (R7-R13, kernel ~31us): L1 touches, DS pipe, global loads,
// barrier count, exp rate each individually eliminated -> all neutral. Only
// unexplored axis: TLP during stall windows at R10's work volume. R10 = 16
// waves/CU (2 blk x 8 w). R14: TPB 1024, grid 512 = 64 b x 8 m-quads ->
// 2 blocks/CU x 16 waves = 32 waves/CU with IDENTICAL per-CU load/VALU work.
// Needs actual VGPR <= 64 for 8 waves/SIMD: launch_bounds(1024,4) -> 64-reg
// budget (measured rule VGPR = 256/min_waves, R1-R5; R5 fit 52).
// Kept (all measured): dense loads (lane=(row,c4), 1 instr = 64 distinct
// 64B lines), quad dot via DPP quad_perm 0xB1/0x4E (VALU), one exp per lane
// (own m = c4) + quad_perm rebroadcast, harvest via row_shl:4/8 only (NO
// xor16/32 shfl - __shfl is ds_bpermute/DS pipe), sub-partials red[64][69]
// (conflict-free stores), single-wave tail, 2 barriers/pass (5 total),
// cheap pass-0, W in LDS stride 65, b = bx&63 pins batch to XCD b%8.

#define TPB 1024

typedef float vf2 __attribute__((ext_vector_type(2)));

// x + dpp_shuffled(x); bound_ctrl=true -> out-of-pattern lanes contribute 0
#define DPP_ADDF(x, ctrl) \
    ((x) + __int_as_float(__builtin_amdgcn_update_dpp( \
        0, __float_as_int(x), (ctrl), 0xF, 0xF, true)))
// pure dpp mov (quad_perm broadcast)
#define DPP_MOVF(x, ctrl) \
    (__int_as_float(__builtin_amdgcn_update_dpp( \
        0, __float_as_int(x), (ctrl), 0xF, 0xF, true)))
// quad_perm xor1 = 0xB1, xor2 = 0x4E; row_shl:4 = 0x104, row_shl:8 = 0x108
// quad_perm bcast lane i: 0x00, 0x55, 0xAA, 0xFF

#define LOG2E 1.44269504088896f

__global__ __launch_bounds__(TPB, 4)
void capsule_routing_kernel(const float* __restrict__ in,
                            const float* __restrict__ W,
                            float* __restrict__ out)
{
    __shared__ float red[64 * 69];   // [wave*4+rowof16][m*17 + {S, xc[16]}]
    __shared__ float cum[64];        // cumulative wv[tmi][d] * LOG2E
    __shared__ float w_lds[16 * 65]; // W[d][tmi*16+c], stride 65

    const int tid = threadIdx.x;
    const int w   = tid >> 6;        // 0..15
    const int l   = tid & 63;
    const int c4  = l & 3;           // dim-quarter of row == own m (qp)
    const int rg  = l >> 4;          // row-of-16 within wave (0..3)
    const int b   = blockIdx.x & 63;
    const int m0  = (blockIdx.x >> 6) << 2;   // 8 m-quads
    const bool qb0 = (l & 1) != 0;   // qp bit 0
    const bool qb1 = (l & 2) != 0;   // qp bit 1

    // dense: lane l reads float4 #(w*512 + g*64 + l); wave w owns rows
    // [w*128, w*128+128), g = 0..7
    const float4* __restrict__ inb4 =
        (const float4*)(in + ((size_t)b << 15)) + ((w << 9) + l);

    // stage W[:, m0:m0+4, :] (1024 floats) -> LDS, stride-65 rows, one per
    // thread. Ordered before first use by pass-0's red barrier.
    {
        const int d = tid >> 6, r = tid & 63;
        w_lds[d * 65 + r] = W[(d << 9) + (m0 << 4) + r];
    }

    float cwv = 0.f;                 // tail-wave cumulative wv (lane = tmi,tc)

    for (int pass = 0; pass < 3; ++pass) {
        vf2 wva[4], wvb[4];
        if (pass) {
            const float4* cp = (const float4*)cum;   // 16-way broadcast reads
            #pragma unroll
            for (int m = 0; m < 4; ++m) {
                const float4 q = cp[(m << 2) + c4];  // cum[m*16 + c4*4 ..+3]
                wva[m].x = q.x; wva[m].y = q.y;
                wvb[m].x = q.z; wvb[m].y = q.w;
            }
        }

        vf2 xa[4], xb[4];
        float Sown = 0.f;            // S partial for m == c4 only
        #pragma unroll
        for (int m = 0; m < 4; ++m) {
            xa[m].x = 0.f; xa[m].y = 0.f;
            xb[m].x = 0.f; xb[m].y = 0.f;
        }

        #pragma unroll 2
        for (int g = 0; g < 8; ++g) {
            const float4 f = inb4[g << 6];
            vf2 fa, fb;
            fa.x = f.x; fa.y = f.y; fb.x = f.z; fb.y = f.w;
            if (pass) {
                float dm[4];
                #pragma unroll
                for (int m = 0; m < 4; ++m) {
                    vf2 t = fa * wva[m] + fb * wvb[m];   // pk_mul + pk_fma
                    float d = t.x + t.y;
                    d = DPP_ADDF(d, 0xB1);               // quad-sum (VALU)
                    d = DPP_ADDF(d, 0x4E);
                    dm[m] = d;
                }
                // one exp per lane (own m), then quad-broadcast all 4 e's
                const float dsel = qb1 ? (qb0 ? dm[3] : dm[2])
                                       : (qb0 ? dm[1] : dm[0]);
                const float eown = exp2f(dsel);          // logits prescaled
                const float e0 = DPP_MOVF(eown, 0x00);
                const float e1 = DPP_MOVF(eown, 0x55);
                const float e2 = DPP_MOVF(eown, 0xAA);
                const float e3 = DPP_MOVF(eown, 0xFF);
                Sown += eown;
                xa[0] += fa * e0; xb[0] += fb * e0;
                xa[1] += fa * e1; xb[1] += fb * e1;
                xa[2] += fa * e2; xb[2] += fb * e2;
                xa[3] += fa * e3; xb[3] += fb * e3;
            } else {                                     // e = 1, m-independent
                xa[0] += fa; xb[0] += fb;
            }
        }

        // harvest: row_shl:4 + row_shl:8 (VALU DPP) -> lanes 0..3 of each
        // row-of-16 hold its c4-group sums (S: lanes 4 apart share c4, so
        // the same shifts sum S[m=c4]). No cross-row shuffle.
        const int pbase = ((w << 2) + rg) * 69;
        if (pass) {
            float vals[16] = { xa[0].x, xa[0].y, xb[0].x, xb[0].y,
                               xa[1].x, xa[1].y, xb[1].x, xb[1].y,
                               xa[2].x, xa[2].y, xb[2].x, xb[2].y,
                               xa[3].x, xa[3].y, xb[3].x, xb[3].y };
            #pragma unroll
            for (int v = 0; v < 16; ++v) {
                float x = vals[v];
                x = DPP_ADDF(x, 0x104);   // lane i += lane i+4
                x = DPP_ADDF(x, 0x108);   // lane i += lane i+8
                vals[v] = x;
            }
            float ss = Sown;
            ss = DPP_ADDF(ss, 0x104);
            ss = DPP_ADDF(ss, 0x108);
            if ((l & 15) < 4) {           // l&15 == c4
                #pragma unroll
                for (int m = 0; m < 4; ++m) {
                    #pragma unroll
                    for (int j = 0; j < 4; ++j)
                        red[pbase + m * 17 + 1 + (c4 << 2) + j] = vals[(m << 2) + j];
                }
                red[pbase + c4 * 17] = ss;    // lane c4 owns S[m=c4]
            }
        } else {
            float vals[4] = { xa[0].x, xa[0].y, xb[0].x, xb[0].y };
            #pragma unroll
            for (int v = 0; v < 4; ++v) {
                float x = vals[v];
                x = DPP_ADDF(x, 0x104);
                x = DPP_ADDF(x, 0x108);
                vals[v] = x;
            }
            if ((l & 15) < 4) {
                #pragma unroll
                for (int j = 0; j < 4; ++j)
                    red[pbase + 1 + (c4 << 2) + j] = vals[j];
            }
        }
        __syncthreads();                  // red ready (also orders W staging)

        // ---- tail: wave 0 only. lane = (tmi = l>>4, tc = l&15) ----
        if (w == 0) {
            const int tmi = rg;           // l>>4
            const int tc  = l & 15;
            float Stot = 0.f, xtot = 0.f;
            if (pass) {
                #pragma unroll 8
                for (int p = 0; p < 64; ++p) {
                    Stot += red[p * 69 + tmi * 17];
                    xtot += red[p * 69 + tmi * 17 + 1 + tc];
                }
            } else {
                Stot = 2048.f;
                #pragma unroll 8
                for (int p = 0; p < 64; ++p)
                    xtot += red[p * 69 + 1 + tc];   // m0 slots; same for all m
            }
            // s(tmi,tc) = (1/S) Sum_d xtot(tmi,d) * W[d][tmi*16+tc]
            float s = 0.f;
            #pragma unroll
            for (int d = 0; d < 16; ++d)
                s += __shfl(xtot, (tmi << 4) + d) * w_lds[d * 65 + (tmi << 4) + tc];
            s /= Stot;
            float n2 = s * s;
            n2 += __shfl_xor(n2, 1);
            n2 += __shfl_xor(n2, 2);
            n2 += __shfl_xor(n2, 4);
            n2 += __shfl_xor(n2, 8);
            const float nr = sqrtf(n2);
            const float v  = s * (n2 / (1.f + n2)) / (nr + 1e-7f);
            if (pass < 2) {
                float wvv = 0.f;          // wv(tmi, d=tc)
                #pragma unroll
                for (int c2 = 0; c2 < 16; ++c2)
                    wvv += w_lds[tc * 65 + (tmi << 4) + c2] * __shfl(v, (tmi << 4) + c2);
                cwv += wvv;               // raw accumulation across passes
                cum[(tmi << 4) + tc] = cwv * LOG2E;   // prescale for exp2
            } else {
                out[((size_t)b << 9) + ((m0 + tmi) << 4) + tc] = v;
            }
        }
        if (pass < 2) __syncthreads();    // cum ready; red free for next pass
    }
}

extern "C" void kernel_launch(void* const* d_in, const int* in_sizes, int n_in,
                              void* d_out, int out_size, void* d_ws, size_t ws_size,
                              hipStream_t stream) {
    (void)in_sizes; (void)n_in; (void)d_ws; (void)ws_size; (void)out_size;
    const float* in = (const float*)d_in[0];
    const float* W  = (const float*)d_in[1];
    float* out = (float*)d_out;
    hipLaunchKernelGGL(capsule_routing_kernel, dim3(512), dim3(TPB), 0, stream,
                       in, W, out);
}

// Round 15
// 71.249 us; speedup vs baseline: 1.2059x; 1.2059x over previous
//
#include <hip/hip_runtime.h>
#include <math.h>

// CapsuleLayer routing via MFMA (u_hat never materialized):
//   logit[n,m] = in[n,:] @ cumwv[:,m]        (K=16, bf16 MFMA, C: row=n,col=m)
//   e = exp2(logit)  (cumwv prescaled by log2 e)
//   xc[m,d] = sum_n e[n,m] in[n,d]; S[m] = sum_n e[n,m]
//   s = (xc/S) @ W_m (fp32 tail); v = squash(s); cumwv += W_m @ v
// Layout trick (m89/m120-verified): C-frag(logit) == A-frag(E^T) for the xc
// MFMA up to an n-regroup across quads -> tiny per-wave LDS round-trip.
// Precision: logits ~0.01, softmax near-uniform; bf16 errors average over
// 2048 n -> v error ~1e-3 << 1.13e-2 threshold.
// R7-R14 ledger: every throughput axis (L1/DS/loads/barriers/exp/TLP) is
// falsified as the wall; residual = cross-lane dependency-chain latency.
// MFMA replaces the chains entirely.
// Grid 128 = 64 b x 2 m-halves (16 m); TPB 512 (8 waves, 256 n each);
// LDS ~150 KB -> 1 block/CU. b = bx&63 keeps batch XCD-local.

#define TPB 512
#define LOG2E 1.44269504088896f

typedef __attribute__((ext_vector_type(8))) short short8;   // 8 bf16 = 4 VGPR
typedef __attribute__((ext_vector_type(4))) float float4v;  // MFMA acc

#define DPP_ADDF(x, ctrl) \
    ((x) + __int_as_float(__builtin_amdgcn_update_dpp( \
        0, __float_as_int(x), (ctrl), 0xF, 0xF, true)))
// row_shl:4 = 0x104, row_shl:8 = 0x108

static __device__ inline unsigned short f2bf(float x) {     // RNE f32->bf16
    unsigned u = __float_as_uint(x);
    return (unsigned short)((u + 0x7FFFu + ((u >> 16) & 1u)) >> 16);
}
static __device__ inline unsigned pk2(float a, float b) {
    return (unsigned)f2bf(a) | ((unsigned)f2bf(b) << 16);
}

__global__ __launch_bounds__(TPB, 2)
void capsule_routing_kernel(const float* __restrict__ in,
                            const float* __restrict__ W,
                            float* __restrict__ out)
{
    __shared__ unsigned short innorm[2048 * 16];   // bf16 in[n][d]       64 KB
    __shared__ unsigned short inT[16 * 2056];      // bf16 in^T[d][n]+pad 64.3 KB
    __shared__ unsigned short e_all[8][16 * 36];   // per-wave e[m][n32]   9 KB
    __shared__ float red[8 * 288];                 // [w][m*17+d], S at 272+m
    __shared__ float sum0[32 * 20];                // pass-0 colsum partials
    __shared__ unsigned short cum_lds[16 * 16];    // bf16 cumwv*LOG2E [d][m]

    const int tid  = threadIdx.x;
    const int w    = tid >> 6;
    const int l    = tid & 63;
    const int ml   = l & 15;        // MFMA row/col owner index
    const int quad = l >> 4;        // 0..3
    const int b    = blockIdx.x & 63;
    const int m0g  = (blockIdx.x >> 6) << 4;   // 0 or 16

    // ---- stage: read in[b] fp32 (dense float4), write bf16 norm + transposed,
    //      and accumulate pass-0 column sums on the fly.
    {
        const float4* gin = (const float4*)(in + ((size_t)b << 15));
        float c0 = 0.f, c1 = 0.f, c2 = 0.f, c3 = 0.f;
        const int d0 = (tid & 3) * 4;
        #pragma unroll
        for (int k = 0; k < 16; ++k) {
            const int idx = tid + TPB * k;
            const float4 g = gin[idx];
            const int n = idx >> 2;
            c0 += g.x; c1 += g.y; c2 += g.z; c3 += g.w;
            const unsigned short u0 = f2bf(g.x), u1 = f2bf(g.y),
                                 u2 = f2bf(g.z), u3 = f2bf(g.w);
            uint2 pk; pk.x = (unsigned)u0 | ((unsigned)u1 << 16);
                      pk.y = (unsigned)u2 | ((unsigned)u3 << 16);
            *(uint2*)&innorm[n * 16 + d0] = pk;          // 8B aligned
            inT[(d0 + 0) * 2056 + n] = u0;
            inT[(d0 + 1) * 2056 + n] = u1;
            inT[(d0 + 2) * 2056 + n] = u2;
            inT[(d0 + 3) * 2056 + n] = u3;
        }
        // harvest colsum: row_shl:4/8 -> lanes (l&15)<4 hold row-of-16 sums
        c0 = DPP_ADDF(c0, 0x104); c0 = DPP_ADDF(c0, 0x108);
        c1 = DPP_ADDF(c1, 0x104); c1 = DPP_ADDF(c1, 0x108);
        c2 = DPP_ADDF(c2, 0x104); c2 = DPP_ADDF(c2, 0x108);
        c3 = DPP_ADDF(c3, 0x104); c3 = DPP_ADDF(c3, 0x108);
        if ((l & 15) < 4) {
            float4 v4; v4.x = c0; v4.y = c1; v4.z = c2; v4.w = c3;
            *(float4*)&sum0[((w << 2) + quad) * 20 + (l & 3) * 4] = v4;
        }
    }
    __syncthreads();

    float cwv = 0.f;   // tail threads: cumulative wv[m][d=tc], fp32

    for (int pass = 0; pass < 3; ++pass) {
        // ---------- sweep (passes 1,2 only): MFMA chunks of 32 n ----------
        if (pass) {
            // B-frag (cumwv): B[k=d][m=ml]; k = quad*8+j, zero for k>=16
            short8 bc = {0,0,0,0,0,0,0,0};
            if (quad < 2) {
                #pragma unroll
                for (int j = 0; j < 8; ++j)
                    bc[j] = (short)cum_lds[(quad * 8 + j) * 16 + ml];
            }
            float4v xc = {0.f, 0.f, 0.f, 0.f};
            float Sp = 0.f;
            unsigned short* ew = &e_all[w][0];

            #pragma unroll 2
            for (int t = 0; t < 8; ++t) {
                const int nb = (w << 8) + (t << 5);
                // A-frags (in): A[n=ml][k=d]; quads 2,3 are the zero K-half
                short8 a0 = {0,0,0,0,0,0,0,0};
                short8 a1 = {0,0,0,0,0,0,0,0};
                if (quad < 2) {
                    a0 = *(const short8*)&innorm[(nb + ml) * 16 + quad * 8];
                    a1 = *(const short8*)&innorm[(nb + 16 + ml) * 16 + quad * 8];
                }
                const float4v z = {0.f, 0.f, 0.f, 0.f};
                float4v c0 = __builtin_amdgcn_mfma_f32_16x16x32_bf16(a0, bc, z, 0, 0, 0);
                float4v c1 = __builtin_amdgcn_mfma_f32_16x16x32_bf16(a1, bc, z, 0, 0, 0);
                // e = exp2(logit); C: row n = quad*4+r, col m = ml
                float e00 = exp2f(c0[0]), e01 = exp2f(c0[1]),
                      e02 = exp2f(c0[2]), e03 = exp2f(c0[3]);
                float e10 = exp2f(c1[0]), e11 = exp2f(c1[1]),
                      e12 = exp2f(c1[2]), e13 = exp2f(c1[3]);
                Sp += (e00 + e01) + (e02 + e03) + (e10 + e11) + (e12 + e13);
                uint2 w0; w0.x = pk2(e00, e01); w0.y = pk2(e02, e03);
                uint2 w1; w1.x = pk2(e10, e11); w1.y = pk2(e12, e13);
                *(uint2*)&ew[ml * 36 + quad * 4]      = w0;   // n_local 4q..+3
                *(uint2*)&ew[ml * 36 + 16 + quad * 4] = w1;   // n_local 16+4q..
                // A-frag(E^T): e[m=ml][n_local = quad*8+j]
                union { uint2 u2v[2]; short8 s; } ua;
                ua.u2v[0] = *(const uint2*)&ew[ml * 36 + quad * 8];
                ua.u2v[1] = *(const uint2*)&ew[ml * 36 + quad * 8 + 4];
                // B-frag (in): B[k=n_local][d=ml] from transposed copy
                const short8 bi = *(const short8*)&inT[ml * 2056 + nb + quad * 8];
                xc = __builtin_amdgcn_mfma_f32_16x16x32_bf16(ua.s, bi, xc, 0, 0, 0);
            }
            // S: reduce over quads (same m = ml)
            Sp += __shfl_xor(Sp, 16);
            Sp += __shfl_xor(Sp, 32);
            if (l < 16) red[w * 288 + 272 + l] = Sp;
            // xc C-frag: row m = quad*4+r, col d = ml
            #pragma unroll
            for (int r = 0; r < 4; ++r)
                red[w * 288 + (quad * 4 + r) * 17 + ml] = xc[r];
        }
        __syncthreads();   // red / sum0 ready (and staging on pass 0)

        // ---------- tail: 4 waves, thread = (m = tid>>4, tc = tid&15) ------
        if (tid < 256) {
            const int m  = tid >> 4;
            const int tc = tid & 15;
            const int lbase = tid & 48;
            float Stot, xtot = 0.f;
            if (pass == 0) {
                Stot = 2048.f;
                #pragma unroll 8
                for (int q = 0; q < 32; ++q) xtot += sum0[q * 20 + tc];
            } else {
                Stot = 0.f;
                #pragma unroll
                for (int w2 = 0; w2 < 8; ++w2) {
                    Stot += red[w2 * 288 + 272 + m];
                    xtot += red[w2 * 288 + m * 17 + tc];
                }
            }
            // s(m,tc) = (1/S) sum_d xtot(m,d) * W[d][m0g+m][tc]  (fp32, W global)
            float s = 0.f;
            #pragma unroll
            for (int d = 0; d < 16; ++d)
                s += __shfl(xtot, lbase + d) * W[(d << 9) + ((m0g + m) << 4) + tc];
            s /= Stot;
            float n2 = s * s;
            n2 += __shfl_xor(n2, 1);
            n2 += __shfl_xor(n2, 2);
            n2 += __shfl_xor(n2, 4);
            n2 += __shfl_xor(n2, 8);
            const float nr = sqrtf(n2);
            const float v  = s * (n2 / (1.f + n2)) / (nr + 1e-7f);
            if (pass < 2) {
                float wvv = 0.f;   // wv(m, d=tc)
                #pragma unroll
                for (int c2 = 0; c2 < 16; ++c2)
                    wvv += W[(tc << 9) + ((m0g + m) << 4) + c2] * __shfl(v, lbase + c2);
                cwv += wvv;
                cum_lds[tc * 16 + m] = f2bf(cwv * LOG2E);
            } else {
                out[((size_t)b << 9) + ((m0g + m) << 4) + tc] = v;
            }
        }
        if (pass < 2) __syncthreads();   // cum ready for next sweep
    }
}

extern "C" void kernel_launch(void* const* d_in, const int* in_sizes, int n_in,
                              void* d_out, int out_size, void* d_ws, size_t ws_size,
                              hipStream_t stream) {
    (void)in_sizes; (void)n_in; (void)d_ws; (void)ws_size; (void)out_size;
    const float* in = (const float*)d_in[0];
    const float* W  = (const float*)d_in[1];
    float* out = (float*)d_out;
    hipLaunchKernelGGL(capsule_routing_kernel, dim3(128), dim3(TPB), 0, stream,
                       in, W, out);
}

// Round 16
// 70.041 us; speedup vs baseline: 1.2267x; 1.0172x over previous
//
#include <hip/hip_runtime.h>
#include <math.h>

// CapsuleLayer routing via MFMA (u_hat never materialized):
//   logit[n,m] = in[n,:] @ cumwv[:,m]     (K=16 in bf16 MFMA, C: row=n,col=m)
//   e = exp2(logit)   (cumwv prescaled by log2 e)
//   xc[m,d] = sum_n e[n,m] in[n,d]; S[m] = sum_n e[n,m]   (E^T @ in, MFMA)
//   s = (xc/S) @ W_m (fp32 tail); v = squash(s); cumwv += W_m @ v
// C-frag(logit) == A-frag(E^T) up to an n-regroup across quads (per-wave LDS
// round-trip) [R15-verified, absmax 1.95e-3 vs 1.13e-2 threshold].
//
// R15 (TPB 512, 8 waves = 2/SIMD) ran ~23us: latency-exposed per-t chain
// (ds_read->MFMA->8 exp2->pack->LDS->MFMA) with almost no TLP. R16: TPB 1024
// (16 waves = 4/SIMD, 2x latency hiding; per-wave sweep 4 t-iters; staging
// 8 iters). LDS fits by TIME-MULTIPLEXING one 1280B/wave scratch region:
// staging colsum partials -> per-t e-buffer -> xc/S reduction slots (each
// use dead before the next; barriers order cross-wave access). Total
// ~149 KB -> 1 block/CU. Grid 128 = 64 b x 2 m-halves (b = bx&63 XCD-pins).
// launch_bounds(1024,2) -> 128-reg budget (measured rule VGPR=256/min_waves).

#define TPB 1024
#define LOG2E 1.44269504088896f

typedef __attribute__((ext_vector_type(8))) short short8;   // 8 bf16 = 4 VGPR
typedef __attribute__((ext_vector_type(4))) float float4v;  // MFMA acc

#define DPP_ADDF(x, ctrl) \
    ((x) + __int_as_float(__builtin_amdgcn_update_dpp( \
        0, __float_as_int(x), (ctrl), 0xF, 0xF, true)))
// row_shl:4 = 0x104, row_shl:8 = 0x108

static __device__ inline unsigned short f2bf(float x) {     // RNE f32->bf16
    unsigned u = __float_as_uint(x);
    return (unsigned short)((u + 0x7FFFu + ((u >> 16) & 1u)) >> 16);
}
static __device__ inline unsigned pk2(float a, float b) {
    return (unsigned)f2bf(a) | ((unsigned)f2bf(b) << 16);
}

__global__ __launch_bounds__(TPB, 2)
void capsule_routing_kernel(const float* __restrict__ in,
                            const float* __restrict__ W,
                            float* __restrict__ out)
{
    __shared__ unsigned short innorm[2048 * 16];   // bf16 in[n][d]        64 KB
    __shared__ unsigned short inT[16 * 2056];      // bf16 in^T[d][n]+pad  64.3 KB
    __shared__ float scratch[16][320];             // per-wave multiplex   20 KB:
        // staging: colsum partials [quad*20 + d]  (sum over lane's n's)
        // sweep:   e-buffer (576 shorts, ml*36 + n_local)
        // reduce:  xc [m*17 + d] (m=quad*4+r, d=ml), S at [272+ml]
    __shared__ unsigned short cum_lds[16 * 16];    // bf16 cumwv*LOG2E [d][m]

    const int tid  = threadIdx.x;
    const int w    = tid >> 6;       // 0..15
    const int l    = tid & 63;
    const int ml   = l & 15;         // MFMA row/col owner index
    const int quad = l >> 4;         // 0..3
    const int b    = blockIdx.x & 63;
    const int m0g  = (blockIdx.x >> 6) << 4;   // 0 or 16

    // ---- stage: fp32 dense float4 reads -> bf16 innorm + transposed inT,
    //      pass-0 column-sum partials on the fly (into scratch).
    {
        const float4* gin = (const float4*)(in + ((size_t)b << 15));
        float c0 = 0.f, c1 = 0.f, c2 = 0.f, c3 = 0.f;
        const int d0 = (tid & 3) * 4;
        #pragma unroll
        for (int k = 0; k < 8; ++k) {
            const int idx = tid + TPB * k;
            const float4 g = gin[idx];
            const int n = idx >> 2;
            c0 += g.x; c1 += g.y; c2 += g.z; c3 += g.w;
            const unsigned short u0 = f2bf(g.x), u1 = f2bf(g.y),
                                 u2 = f2bf(g.z), u3 = f2bf(g.w);
            uint2 pk; pk.x = (unsigned)u0 | ((unsigned)u1 << 16);
                      pk.y = (unsigned)u2 | ((unsigned)u3 << 16);
            *(uint2*)&innorm[n * 16 + d0] = pk;          // 8B aligned
            inT[(d0 + 0) * 2056 + n] = u0;               // ~4-way banks: ok
            inT[(d0 + 1) * 2056 + n] = u1;
            inT[(d0 + 2) * 2056 + n] = u2;
            inT[(d0 + 3) * 2056 + n] = u3;
        }
        // harvest colsum: row_shl:4/8 -> lanes (l&15)<4 hold 16-lane-group
        // sums for their d0 block (lanes i,i+4,i+8,i+12 share d0)
        c0 = DPP_ADDF(c0, 0x104); c0 = DPP_ADDF(c0, 0x108);
        c1 = DPP_ADDF(c1, 0x104); c1 = DPP_ADDF(c1, 0x108);
        c2 = DPP_ADDF(c2, 0x104); c2 = DPP_ADDF(c2, 0x108);
        c3 = DPP_ADDF(c3, 0x104); c3 = DPP_ADDF(c3, 0x108);
        if ((l & 15) < 4) {
            float4 v4; v4.x = c0; v4.y = c1; v4.z = c2; v4.w = c3;
            *(float4*)&scratch[w][quad * 20 + (l & 3) * 4] = v4;
        }
    }

    float cwv = 0.f;   // tail threads: cumulative wv[m][d=tc], fp32

    for (int pass = 0; pass < 3; ++pass) {
        // ---------- sweep (passes 1,2): MFMA chunks of 32 n ----------
        if (pass) {
            // B-frag (cumwv): B[k=d][m=ml]; k = quad*8+j, zero for k>=16
            short8 bc = {0,0,0,0,0,0,0,0};
            if (quad < 2) {
                #pragma unroll
                for (int j = 0; j < 8; ++j)
                    bc[j] = (short)cum_lds[(quad * 8 + j) * 16 + ml];
            }
            float4v xc = {0.f, 0.f, 0.f, 0.f};
            float Sp = 0.f;
            unsigned short* ew = (unsigned short*)&scratch[w][0];  // e-buffer

            #pragma unroll 2
            for (int t = 0; t < 4; ++t) {
                const int nb = (w << 7) + (t << 5);     // wave owns 128 n
                // A-frags (in): A[n=ml][k=d]; quads 2,3 are the zero K-half
                short8 a0 = {0,0,0,0,0,0,0,0};
                short8 a1 = {0,0,0,0,0,0,0,0};
                if (quad < 2) {
                    a0 = *(const short8*)&innorm[(nb + ml) * 16 + quad * 8];
                    a1 = *(const short8*)&innorm[(nb + 16 + ml) * 16 + quad * 8];
                }
                const float4v z = {0.f, 0.f, 0.f, 0.f};
                float4v c0 = __builtin_amdgcn_mfma_f32_16x16x32_bf16(a0, bc, z, 0, 0, 0);
                float4v c1 = __builtin_amdgcn_mfma_f32_16x16x32_bf16(a1, bc, z, 0, 0, 0);
                // e = exp2(logit); C: row n = quad*4+r, col m = ml
                float e00 = exp2f(c0[0]), e01 = exp2f(c0[1]),
                      e02 = exp2f(c0[2]), e03 = exp2f(c0[3]);
                float e10 = exp2f(c1[0]), e11 = exp2f(c1[1]),
                      e12 = exp2f(c1[2]), e13 = exp2f(c1[3]);
                Sp += (e00 + e01) + (e02 + e03) + (e10 + e11) + (e12 + e13);
                uint2 w0; w0.x = pk2(e00, e01); w0.y = pk2(e02, e03);
                uint2 w1; w1.x = pk2(e10, e11); w1.y = pk2(e12, e13);
                *(uint2*)&ew[ml * 36 + quad * 4]      = w0;   // n_local 4q..+3
                *(uint2*)&ew[ml * 36 + 16 + quad * 4] = w1;   // n_local 16+4q..
                // A-frag(E^T): e[m=ml][n_local = quad*8+j]
                union { uint2 u2v[2]; short8 s; } ua;
                ua.u2v[0] = *(const uint2*)&ew[ml * 36 + quad * 8];
                ua.u2v[1] = *(const uint2*)&ew[ml * 36 + quad * 8 + 4];
                // B-frag (in): B[k=n_local][d=ml] from transposed copy
                const short8 bi = *(const short8*)&inT[ml * 2056 + nb + quad * 8];
                xc = __builtin_amdgcn_mfma_f32_16x16x32_bf16(ua.s, bi, xc, 0, 0, 0);
            }
            // S: reduce over quads (same m = ml); e-buffer is dead now ->
            // reuse scratch[w] as the reduction slot (own wave only).
            Sp += __shfl_xor(Sp, 16);
            Sp += __shfl_xor(Sp, 32);
            #pragma unroll
            for (int r = 0; r < 4; ++r)
                scratch[w][(quad * 4 + r) * 17 + ml] = xc[r];
            if (l < 16) scratch[w][272 + l] = Sp;
        }
        __syncthreads();   // scratch slots ready (pass 0: staging + colsum)

        // ---------- tail: 4 waves, thread = (m = tid>>4, tc = tid&15) ------
        if (tid < 256) {
            const int m  = tid >> 4;
            const int tc = tid & 15;
            const int lbase = tid & 48;
            float Stot, xtot = 0.f;
            if (pass == 0) {
                Stot = 2048.f;
                #pragma unroll 4
                for (int w2 = 0; w2 < 16; ++w2)
                    #pragma unroll
                    for (int q = 0; q < 4; ++q)
                        xtot += scratch[w2][q * 20 + tc];
            } else {
                Stot = 0.f;
                #pragma unroll 4
                for (int w2 = 0; w2 < 16; ++w2) {
                    Stot += scratch[w2][272 + m];
                    xtot += scratch[w2][m * 17 + tc];
                }
            }
            // s(m,tc) = (1/S) sum_d xtot(m,d) * W[d][m0g+m][tc]  (fp32, W L2-hot)
            float s = 0.f;
            #pragma unroll
            for (int d = 0; d < 16; ++d)
                s += __shfl(xtot, lbase + d) * W[(d << 9) + ((m0g + m) << 4) + tc];
            s /= Stot;
            float n2 = s * s;
            n2 += __shfl_xor(n2, 1);
            n2 += __shfl_xor(n2, 2);
            n2 += __shfl_xor(n2, 4);
            n2 += __shfl_xor(n2, 8);
            const float nr = sqrtf(n2);
            const float v  = s * (n2 / (1.f + n2)) / (nr + 1e-7f);
            if (pass < 2) {
                float wvv = 0.f;   // wv(m, d=tc)
                #pragma unroll
                for (int c2 = 0; c2 < 16; ++c2)
                    wvv += W[(tc << 9) + ((m0g + m) << 4) + c2] * __shfl(v, lbase + c2);
                cwv += wvv;
                cum_lds[tc * 16 + m] = f2bf(cwv * LOG2E);
            } else {
                out[((size_t)b << 9) + ((m0g + m) << 4) + tc] = v;
            }
        }
        if (pass < 2) __syncthreads();   // cum ready; scratch free for sweep
    }
}

extern "C" void kernel_launch(void* const* d_in, const int* in_sizes, int n_in,
                              void* d_out, int out_size, void* d_ws, size_t ws_size,
                              hipStream_t stream) {
    (void)in_sizes; (void)n_in; (void)d_ws; (void)ws_size; (void)out_size;
    const float* in = (const float*)d_in[0];
    const float* W  = (const float*)d_in[1];
    float* out = (float*)d_out;
    hipLaunchKernelGGL(capsule_routing_kernel, dim3(128), dim3(TPB), 0, stream,
                       in, W, out);
}